// Round 6
// baseline (385.798 us; speedup 1.0000x reference)
//
#include <hip/hip_runtime.h>
#include <math.h>

#define LN_EPS 1e-5f

__device__ __forceinline__ float dot4(float4 a, float4 b) {
    return a.x*b.x + a.y*b.y + a.z*b.z + a.w*b.w;
}
__device__ __forceinline__ float fast_sigmoid(float x) {
    return 1.f / (1.f + __expf(-x));
}
__device__ __forceinline__ float fast_tanh(float x) {
    const float e = __expf(2.f * x);
    return 1.f - 2.f / (e + 1.f);
}
// opaque register pin: a value defined by inline asm cannot be rematerialized
__device__ __forceinline__ void pin4(float4& v) {
    asm volatile("" : "+v"(v.x), "+v"(v.y), "+v"(v.z), "+v"(v.w));
}
__device__ __forceinline__ float wsum64(float v) {
    #pragma unroll
    for (int off = 32; off > 0; off >>= 1) v += __shfl_xor(v, off);
    return v;
}

// ---------------------------------------------------------------------------
// Kernel 1: time embedding + {q,k} projection + LN  (+ xm transpose blocks).
// Blocks 0..31: query rows (4/blk). 32..1055: key rows (4/blk) -> kT[b][d][t].
// Blocks 1056..1063: build xm[b][t][c] = (x*mm, mm) float2 (coalesced scan).
// Weight reads use (row, interleaved-chunk) lanes -> fully coalesced.
// ---------------------------------------------------------------------------
__global__ void k_embed_proj(
    const float* __restrict__ input, const float* __restrict__ mask,
    const float* __restrict__ timesteps,
    const float* __restrict__ pw, const float* __restrict__ pb,
    const float* __restrict__ lw, const float* __restrict__ lb,
    const float* __restrict__ q_w, const float* __restrict__ q_b,
    const float* __restrict__ q_g, const float* __restrict__ q_be,
    const float* __restrict__ k_w, const float* __restrict__ k_b,
    const float* __restrict__ k_g, const float* __restrict__ k_be,
    float* __restrict__ qs, float* __restrict__ kT, float2* __restrict__ xm)
{
    const int blk = blockIdx.x;
    const int tid = threadIdx.x;          // 0..127

    __shared__ __align__(16) float e[4][128];
    __shared__ __align__(16) float4 red[128];
    __shared__ __align__(16) float proj[4][128];
    __shared__ __align__(16) float2 tile[32][65];

    if (blk >= 1056) {
        // ---- xm transpose: one block per b ----
        const int b  = blk - 1056;
        const int cg = tid >> 6;          // 0..1
        const int tt = tid & 63;
        for (int t0 = 0; t0 < 512; t0 += 64) {
            for (int c16 = 0; c16 < 16; ++c16) {
                const int c = c16*2 + cg;
                const float m = mask [(size_t)(b*32 + c)*512 + t0 + tt];
                const float x = input[(size_t)(b*32 + c)*512 + t0 + tt];
                const float mm = 1.0f - m;
                tile[c][tt] = make_float2(x*mm, mm);
            }
            __syncthreads();
            const int c2 = tid & 31;
            const int tg = tid >> 5;      // 0..3
            #pragma unroll
            for (int k = 0; k < 16; ++k) {
                const int t = tg*16 + k;
                xm[((size_t)b*512 + t0 + t)*32 + c2] = tile[c2][t];
            }
            __syncthreads();
        }
        return;
    }

    const bool isq = blk < 32;
    float tv[4];
    int kidx0 = 0;
    if (isq) {
        const int q0 = blk * 4;
        #pragma unroll
        for (int r = 0; r < 4; ++r) tv[r] = (float)(q0 + r) * (1.0f/127.0f);
    } else {
        kidx0 = (blk - 32) * 4;
        #pragma unroll
        for (int r = 0; r < 4; ++r) tv[r] = timesteps[kidx0 + r];
    }

    float pwj = 0.f, pbj = 0.f;
    if (tid > 0) { pwj = pw[tid-1]; pbj = pb[tid-1]; }
    const float lw0 = lw[0], lb0 = lb[0];
    #pragma unroll
    for (int r = 0; r < 4; ++r)
        e[r][tid] = (tid == 0) ? (tv[r]*lw0 + lb0) : sinf(tv[r]*pwj + pbj);
    __syncthreads();

    const float* W  = isq ? q_w  : k_w;
    const float* Bv = isq ? q_b  : k_b;
    const float* G  = isq ? q_g  : k_g;
    const float* Be = isq ? q_be : k_be;

    // projection: thread = (jj = tid>>2, dc = tid&3), interleaved chunks
    {
        const int jj = tid >> 2, dc = tid & 3;
        const float4* e0 = (const float4*)(&e[0][0]);
        const float4* e1 = (const float4*)(&e[1][0]);
        const float4* e2 = (const float4*)(&e[2][0]);
        const float4* e3 = (const float4*)(&e[3][0]);
        #pragma unroll
        for (int jb = 0; jb < 4; ++jb) {
            const int j = jb*32 + jj;
            const float4* wrow = (const float4*)(W + (size_t)j*128);
            float a0=0.f, a1=0.f, a2=0.f, a3=0.f;
            #pragma unroll
            for (int k = 0; k < 8; ++k) {
                const int idx = dc + 4*k;     // lanes cover contiguous 64B/4-lanes
                const float4 w4 = wrow[idx];
                a0 += dot4(w4, e0[idx]);
                a1 += dot4(w4, e1[idx]);
                a2 += dot4(w4, e2[idx]);
                a3 += dot4(w4, e3[idx]);
            }
            a0 += __shfl_xor(a0, 1, 4); a0 += __shfl_xor(a0, 2, 4);
            a1 += __shfl_xor(a1, 1, 4); a1 += __shfl_xor(a1, 2, 4);
            a2 += __shfl_xor(a2, 1, 4); a2 += __shfl_xor(a2, 2, 4);
            a3 += __shfl_xor(a3, 1, 4); a3 += __shfl_xor(a3, 2, 4);
            if (dc == 0) {
                const float bj = Bv[j];
                proj[0][j] = a0 + bj; proj[1][j] = a1 + bj;
                proj[2][j] = a2 + bj; proj[3][j] = a3 + bj;
            }
        }
    }
    __syncthreads();

    float acc[4];
    #pragma unroll
    for (int r = 0; r < 4; ++r) acc[r] = proj[r][tid];

    // LayerNorm over 128 for 4 rows at once (float4 tree)
    red[tid] = make_float4(acc[0], acc[1], acc[2], acc[3]);
    __syncthreads();
    for (int s = 64; s > 0; s >>= 1) {
        if (tid < s) {
            float4 m = red[tid]; const float4 o = red[tid+s];
            m.x += o.x; m.y += o.y; m.z += o.z; m.w += o.w;
            red[tid] = m;
        }
        __syncthreads();
    }
    float4 mean = red[0];
    mean.x *= (1.0f/128.0f); mean.y *= (1.0f/128.0f);
    mean.z *= (1.0f/128.0f); mean.w *= (1.0f/128.0f);
    __syncthreads();
    const float d0 = acc[0]-mean.x, d1 = acc[1]-mean.y,
                d2 = acc[2]-mean.z, d3 = acc[3]-mean.w;
    red[tid] = make_float4(d0*d0, d1*d1, d2*d2, d3*d3);
    __syncthreads();
    for (int s = 64; s > 0; s >>= 1) {
        if (tid < s) {
            float4 m = red[tid]; const float4 o = red[tid+s];
            m.x += o.x; m.y += o.y; m.z += o.z; m.w += o.w;
            red[tid] = m;
        }
        __syncthreads();
    }
    float4 var = red[0];
    var.x *= (1.0f/128.0f); var.y *= (1.0f/128.0f);
    var.z *= (1.0f/128.0f); var.w *= (1.0f/128.0f);

    const float gg = G[tid], bb = Be[tid];
    const float o0 = d0*rsqrtf(var.x+LN_EPS)*gg + bb;
    const float o1 = d1*rsqrtf(var.y+LN_EPS)*gg + bb;
    const float o2 = d2*rsqrtf(var.z+LN_EPS)*gg + bb;
    const float o3 = d3*rsqrtf(var.w+LN_EPS)*gg + bb;

    if (isq) {
        const float sc = 0.08838834764831845f;   // 1/sqrt(128)
        const int q0 = blk*4;
        qs[(size_t)(q0+0)*128 + tid] = o0*sc;
        qs[(size_t)(q0+1)*128 + tid] = o1*sc;
        qs[(size_t)(q0+2)*128 + tid] = o2*sc;
        qs[(size_t)(q0+3)*128 + tid] = o3*sc;
    } else {
        // transposed K: kT[b][d][t], 4 consecutive t -> one float4 store
        const int b = kidx0 >> 9;
        const int t = kidx0 & 511;
        *(float4*)(kT + ((size_t)(b*128 + tid))*512 + t) =
            make_float4(o0, o1, o2, o3);
    }
}

// ---------------------------------------------------------------------------
// Kernel 2: attention. 256 blocks = (b, 4 qi), 256 threads.
// Score: coalesced kT stream (lanes along t) shared by 4 queries.
// Scan: coalesced xm float2 stream, 4 qi per read. Reductions via shuffles.
// ---------------------------------------------------------------------------
__global__ void __launch_bounds__(256) k_attn(
    const float2* __restrict__ xm,
    const float* __restrict__ qs, const float* __restrict__ kT,
    const float* __restrict__ attn_g, const float* __restrict__ attn_b,
    const float* __restrict__ out_w, const float* __restrict__ out_b,
    const float* __restrict__ out_g, const float* __restrict__ out_be,
    float* __restrict__ outm)
{
    const int b     = blockIdx.x >> 5;
    const int qbase = (blockIdx.x & 31) * 4;
    const int tid   = threadIdx.x;          // 0..255

    __shared__ __align__(16) float et[4][512];
    __shared__ __align__(16) float qsh[4][128];
    __shared__ __align__(16) float wsh[128*66];   // out_w padded rows
    __shared__ __align__(16) float sA[4][8][32];
    __shared__ __align__(16) float aA[4][8][32];
    __shared__ __align__(16) float x2s[4][64];
    __shared__ float redC[4];

    for (int idx = tid; idx < 512; idx += 256)
        qsh[idx >> 7][idx & 127] = qs[(size_t)(qbase + (idx >> 7))*128 + (idx & 127)];
    for (int idx = tid; idx < 8192; idx += 256)
        wsh[(idx >> 6)*66 + (idx & 63)] = out_w[idx];
    __syncthreads();

    // ---- scores: group (tid>>7) handles 2 qi; thread covers 4 t (float4) ----
    {
        const int grp = tid >> 7;
        const int tl  = tid & 127;
        const int q0  = grp*2;
        const float4* kp = (const float4*)kT + (size_t)b*128*128 + tl;
        float4 a0 = make_float4(0,0,0,0), a1 = make_float4(0,0,0,0);
        for (int d = 0; d < 128; ++d) {
            const float4 kv = kp[(size_t)d*128];
            const float qa = qsh[q0][d], qb = qsh[q0+1][d];
            a0.x += qa*kv.x; a0.y += qa*kv.y; a0.z += qa*kv.z; a0.w += qa*kv.w;
            a1.x += qb*kv.x; a1.y += qb*kv.y; a1.z += qb*kv.z; a1.w += qb*kv.w;
        }
        a0.x = __expf(a0.x); a0.y = __expf(a0.y); a0.z = __expf(a0.z); a0.w = __expf(a0.w);
        a1.x = __expf(a1.x); a1.y = __expf(a1.y); a1.z = __expf(a1.z); a1.w = __expf(a1.w);
        ((float4*)et[q0])[tl]   = a0;
        ((float4*)et[q0+1])[tl] = a1;
    }
    __syncthreads();

    // ---- masked scan: thread = (c = tid&31, seg = tid>>5), 4 qi at once ----
    {
        const int c   = tid & 31;
        const int seg = tid >> 5;            // 0..7, 64 t each
        const float2* xp = xm + ((size_t)b*512 + seg*64)*32 + c;
        float s0=0,s1=0,s2=0,s3=0, a0=0,a1=0,a2=0,a3=0;
        #pragma unroll 4
        for (int i = 0; i < 64; ++i) {
            const float2 v = xp[(size_t)i*32];
            const int t = seg*64 + i;
            const float w0 = et[0][t]*v.y, w1 = et[1][t]*v.y;
            const float w2 = et[2][t]*v.y, w3 = et[3][t]*v.y;
            s0 += w0; s1 += w1; s2 += w2; s3 += w3;
            a0 += w0*v.x; a1 += w1*v.x; a2 += w2*v.x; a3 += w3*v.x;
        }
        sA[0][seg][c]=s0; sA[1][seg][c]=s1; sA[2][seg][c]=s2; sA[3][seg][c]=s3;
        aA[0][seg][c]=a0; aA[1][seg][c]=a1; aA[2][seg][c]=a2; aA[3][seg][c]=a3;
    }
    __syncthreads();

    // ---- attv + LN64 (wave = one qi, lanes = 64 channels, shuffle-reduce) ----
    {
        const int ql = tid >> 6;
        const int c2 = tid & 63;
        const int cc = c2 & 31;
        float ss = 0.f;
        #pragma unroll
        for (int g = 0; g < 8; ++g) ss += sA[ql][g][cc];
        float attv;
        if (c2 < 32) {
            float aa = 0.f;
            #pragma unroll
            for (int g = 0; g < 8; ++g) aa += aA[ql][g][cc];
            attv = (ss > 0.f) ? aa/ss : 0.f;
        } else {
            attv = (ss > 0.f) ? 1.0f : 0.0f;   // x == unmask indicator
        }
        const float mean = wsum64(attv) * (1.0f/64.0f);
        const float dv = attv - mean;
        const float var = wsum64(dv*dv) * (1.0f/64.0f);
        x2s[ql][c2] = dv*rsqrtf(var+LN_EPS)*attn_g[c2] + attn_b[c2];
    }
    __syncthreads();

    // ---- out linear (128x64 from LDS) + LN128 ----
    {
        const int jhalf = tid >> 7;
        const int j     = tid & 127;
        const int wave  = tid >> 6;
        for (int lq2 = 0; lq2 < 2; ++lq2) {
            const int ql = jhalf*2 + lq2;
            float acc = out_b[j];
            const float4* wrow = (const float4*)(wsh + j*66);
            const float4* xr   = (const float4*)x2s[ql];
            #pragma unroll
            for (int k = 0; k < 16; ++k) acc += dot4(wrow[k], xr[k]);

            float v = wsum64(acc);
            if ((tid & 63) == 0) redC[wave] = v;
            __syncthreads();
            const float mean = (redC[jhalf*2] + redC[jhalf*2+1]) * (1.0f/128.0f);
            __syncthreads();
            const float d = acc - mean;
            v = wsum64(d*d);
            if ((tid & 63) == 0) redC[wave] = v;
            __syncthreads();
            const float var = (redC[jhalf*2] + redC[jhalf*2+1]) * (1.0f/128.0f);
            outm[((size_t)b*128 + qbase + ql)*128 + j] =
                d*rsqrtf(var+LN_EPS)*out_g[j] + out_be[j];
            __syncthreads();
        }
    }
}

// ---------------------------------------------------------------------------
// Kernel 3: gi[qi][b][g] = outm[b,qi,:]·wih[g,:] + bih[g]
// thread = (g0 = tid>>2, dc = tid&3), interleaved chunks -> coalesced wih.
// ---------------------------------------------------------------------------
__global__ void k_gi(const float* __restrict__ outm,
                     const float* __restrict__ wih, const float* __restrict__ bih,
                     float* __restrict__ gi)
{
    const int qi  = blockIdx.x;
    const int tid = threadIdx.x;   // 0..383
    __shared__ __align__(16) float rows[8][128];
    for (int idx = tid; idx < 1024; idx += 384) {
        const int b = idx >> 7, d = idx & 127;
        rows[b][d] = outm[(size_t)(b*128+qi)*128 + d];
    }
    __syncthreads();

    const int g0 = tid >> 2, dc = tid & 3;
    #pragma unroll
    for (int gb = 0; gb < 4; ++gb) {
        const int g = gb*96 + g0;
        const float4* wrow = (const float4*)(wih + (size_t)g*128);
        float acc[8] = {0,0,0,0,0,0,0,0};
        #pragma unroll
        for (int k = 0; k < 8; ++k) {
            const int idx = dc + 4*k;
            const float4 w4 = wrow[idx];
            #pragma unroll
            for (int b = 0; b < 8; ++b)
                acc[b] += dot4(w4, ((const float4*)rows[b])[idx]);
        }
        #pragma unroll
        for (int b = 0; b < 8; ++b) {
            acc[b] += __shfl_xor(acc[b], 1, 4);
            acc[b] += __shfl_xor(acc[b], 2, 4);
        }
        if (dc == 0) {
            const float bi = bih[g];
            #pragma unroll
            for (int b = 0; b < 8; ++b)
                gi[((size_t)qi*8 + b)*384 + g] = acc[b] + bi;
        }
    }
}

// ---------------------------------------------------------------------------
// Kernel 4: GRU + fused classifier. One block per batch row, 256 threads.
// Thread (s=tid>>7, u=tid&127) computes 3 gate rows over a 64-float k-slice.
// amdgpu_waves_per_eu(1,1): launch_bounds' 2nd arg is only a MIN-occupancy
// guarantee (reg upper bound) -- the scheduler still TARGETS ~4 waves/EU and
// either sank weight loads into the loop (R4: L2 re-stream, 2620 cyc/step)
// or spilled the pinned values to scratch (R5: 3770 cyc/step, VGPR=116).
// waves_per_eu(1,1) sets the occupancy target itself -> 512-VGPR budget ->
// 192 weight VGPRs stay resident. pin4 guards against remat-sinking.
// ---------------------------------------------------------------------------
__global__ void __launch_bounds__(256)
__attribute__((amdgpu_waves_per_eu(1, 1)))
k_gru_cls(
    const float* __restrict__ gi,
    const float* __restrict__ whh, const float* __restrict__ bhh,
    const float* __restrict__ c1w, const float* __restrict__ c1b,
    const float* __restrict__ c2w, const float* __restrict__ c2b,
    const float* __restrict__ c3w, const float* __restrict__ c3b,
    float* __restrict__ out)
{
    const int b   = blockIdx.x;
    const int tid = threadIdx.x;                 // 0..255
    const int s   = tid >> 7;                    // k-half
    const int u   = tid & 127;                   // hidden unit

    __shared__ __align__(16) float h[2][128];
    __shared__ __align__(16) float part3[3][128];

    float4 wr[16], wz[16], wn[16];
    {
        const float4* pr = (const float4*)(whh + (size_t)u*128       + s*64);
        const float4* pz = (const float4*)(whh + (size_t)(u+128)*128 + s*64);
        const float4* pn = (const float4*)(whh + (size_t)(u+256)*128 + s*64);
        #pragma unroll
        for (int i = 0; i < 16; ++i) { wr[i] = pr[i]; wz[i] = pz[i]; wn[i] = pn[i]; }
        #pragma unroll
        for (int i = 0; i < 16; ++i) { pin4(wr[i]); pin4(wz[i]); pin4(wn[i]); }
    }

    const float* gbase = gi + (size_t)b*384;     // + qi*3072 per step
    float bh_r=0.f, bh_z=0.f, bh_n=0.f, gr0=0.f, gz0=0.f, gn0=0.f, hprev=0.f;
    if (s == 0) {
        bh_r = bhh[u]; bh_z = bhh[u+128]; bh_n = bhh[u+256];
        gr0 = gbase[u]; gz0 = gbase[u+128]; gn0 = gbase[u+256];
        h[0][u] = 0.f;
    }
    __syncthreads();

    int p = 0;
    for (int qi = 0; qi < 128; ++qi) {
        const float4* h4 = (const float4*)(&h[p][s*64]);
        float ar = 0.f, az = 0.f, an = 0.f;
        #pragma unroll
        for (int i = 0; i < 16; ++i) {
            const float4 hv = h4[i];
            ar += dot4(wr[i], hv);
            az += dot4(wz[i], hv);
            an += dot4(wn[i], hv);
        }
        if (s == 1) { part3[0][u] = ar; part3[1][u] = az; part3[2][u] = an; }

        float grn=0.f, gzn=0.f, gnn=0.f;
        if (s == 0 && qi < 127) {
            const float* gb = gbase + (size_t)(qi+1)*3072;
            grn = gb[u]; gzn = gb[u+128]; gnn = gb[u+256];
        }
        __syncthreads();

        if (s == 0) {
            const float ghr = ar + part3[0][u] + bh_r;
            const float ghz = az + part3[1][u] + bh_z;
            const float ghn = an + part3[2][u] + bh_n;
            const float r = fast_sigmoid(gr0 + ghr);
            const float z = fast_sigmoid(gz0 + ghz);
            const float n = fast_tanh(gn0 + r*ghn);
            const float hn2 = (1.f - z)*n + z*hprev;
            h[1-p][u] = hn2;
            hprev = hn2;
            gr0 = grn; gz0 = gzn; gn0 = gnn;
        }
        __syncthreads();
        p ^= 1;
    }

    // ---- fused classifier MLP (threads 0..127; h[p] = last hidden) ----
    if (tid < 128) {
        float acc = c1b[u];
        const float4* wc = (const float4*)(c1w + (size_t)u*128);
        const float4* v  = (const float4*)h[p];
        #pragma unroll
        for (int d4 = 0; d4 < 32; ++d4) acc += dot4(wc[d4], v[d4]);
        part3[0][u] = fmaxf(acc, 0.f);
    }
    __syncthreads();
    if (tid < 128) {
        float acc = c2b[u];
        const float4* wc = (const float4*)(c2w + (size_t)u*128);
        const float4* v  = (const float4*)part3[0];
        #pragma unroll
        for (int d4 = 0; d4 < 32; ++d4) acc += dot4(wc[d4], v[d4]);
        part3[1][u] = fmaxf(acc, 0.f);
    }
    __syncthreads();
    if (tid < 2) {
        float acc = c3b[tid];
        const float4* wc = (const float4*)(c3w + (size_t)tid*128);
        const float4* v  = (const float4*)part3[1];
        #pragma unroll
        for (int d4 = 0; d4 < 32; ++d4) acc += dot4(wc[d4], v[d4]);
        out[(size_t)b*2 + tid] = acc;
    }
}

// ---------------------------------------------------------------------------
extern "C" void kernel_launch(void* const* d_in, const int* in_sizes, int n_in,
                              void* d_out, int out_size, void* d_ws, size_t ws_size,
                              hipStream_t stream)
{
    const float* input     = (const float*)d_in[0];
    const float* mask      = (const float*)d_in[1];
    const float* timesteps = (const float*)d_in[2];
    const float* pw        = (const float*)d_in[3];
    const float* pb        = (const float*)d_in[4];
    const float* lw        = (const float*)d_in[5];
    const float* lb        = (const float*)d_in[6];
    const float* q_w       = (const float*)d_in[7];
    const float* q_b       = (const float*)d_in[8];
    const float* q_g       = (const float*)d_in[9];
    const float* q_be      = (const float*)d_in[10];
    const float* k_w       = (const float*)d_in[11];
    const float* k_b       = (const float*)d_in[12];
    const float* k_g       = (const float*)d_in[13];
    const float* k_be      = (const float*)d_in[14];
    const float* attn_g    = (const float*)d_in[15];
    const float* attn_b    = (const float*)d_in[16];
    const float* out_w     = (const float*)d_in[17];
    const float* out_b     = (const float*)d_in[18];
    const float* out_g     = (const float*)d_in[19];
    const float* out_be    = (const float*)d_in[20];
    const float* gru_wih   = (const float*)d_in[21];
    const float* gru_whh   = (const float*)d_in[22];
    const float* gru_bih   = (const float*)d_in[23];
    const float* gru_bhh   = (const float*)d_in[24];
    const float* c1_w      = (const float*)d_in[25];
    const float* c1_b      = (const float*)d_in[26];
    const float* c2_w      = (const float*)d_in[27];
    const float* c2_b      = (const float*)d_in[28];
    const float* c3_w      = (const float*)d_in[29];
    const float* c3_b      = (const float*)d_in[30];

    float* ws   = (float*)d_ws;
    float*  qs   = ws;                    // 128*128             = 16384
    float*  kT   = qs   + 16384;          // 8*128*512           = 524288
    float*  outm = kT   + 524288;         // 8*128*128           = 131072
    float*  gi   = outm + 131072;         // 128*8*384           = 393216
    float2* xm   = (float2*)(gi + 393216);// 8*512*32 float2     = 262144 floats

    k_embed_proj<<<1064, 128, 0, stream>>>(input, mask, timesteps,
                                           pw, pb, lw, lb,
                                           q_w, q_b, q_g, q_be,
                                           k_w, k_b, k_g, k_be, qs, kT, xm);
    k_attn<<<256, 256, 0, stream>>>(xm, qs, kT,
                                    attn_g, attn_b, out_w, out_b,
                                    out_g, out_be, outm);
    k_gi<<<128, 384, 0, stream>>>(outm, gru_wih, gru_bih, gi);
    k_gru_cls<<<8, 256, 0, stream>>>(gi, gru_whh, gru_bhh,
                                     c1_w, c1_b, c2_w, c2_b, c3_w, c3_b,
                                     (float*)d_out);
}

// Round 7
// 262.470 us; speedup vs baseline: 1.4699x; 1.4699x over previous
//
#include <hip/hip_runtime.h>
#include <math.h>

#define LN_EPS 1e-5f

typedef _Float16 h2v __attribute__((ext_vector_type(2)));

__device__ __forceinline__ float dot4(float4 a, float4 b) {
    return a.x*b.x + a.y*b.y + a.z*b.z + a.w*b.w;
}
__device__ __forceinline__ float fast_sigmoid(float x) {
    return 1.f / (1.f + __expf(-x));
}
__device__ __forceinline__ float fast_tanh(float x) {
    const float e = __expf(2.f * x);
    return 1.f - 2.f / (e + 1.f);
}
__device__ __forceinline__ float fdot2u(unsigned int a, unsigned int b, float c) {
#if __has_builtin(__builtin_amdgcn_fdot2)
    return __builtin_amdgcn_fdot2(__builtin_bit_cast(h2v, a),
                                  __builtin_bit_cast(h2v, b), c, false);
#else
    const h2v av = __builtin_bit_cast(h2v, a);
    const h2v bv = __builtin_bit_cast(h2v, b);
    return c + (float)av[0]*(float)bv[0] + (float)av[1]*(float)bv[1];
#endif
}
__device__ __forceinline__ float wsum64(float v) {
    #pragma unroll
    for (int off = 32; off > 0; off >>= 1) v += __shfl_xor(v, off);
    return v;
}

// ---------------------------------------------------------------------------
// Kernel 1: time embedding + {q,k} projection + LN  (+ xm transpose blocks).
// Blocks 0..31: query rows (4/blk). 32..1055: key rows (4/blk) -> kT[b][d][t].
// Blocks 1056..1063: build xm[b][t][c] = (x*mm, mm) float2 (coalesced scan).
// ---------------------------------------------------------------------------
__global__ void k_embed_proj(
    const float* __restrict__ input, const float* __restrict__ mask,
    const float* __restrict__ timesteps,
    const float* __restrict__ pw, const float* __restrict__ pb,
    const float* __restrict__ lw, const float* __restrict__ lb,
    const float* __restrict__ q_w, const float* __restrict__ q_b,
    const float* __restrict__ q_g, const float* __restrict__ q_be,
    const float* __restrict__ k_w, const float* __restrict__ k_b,
    const float* __restrict__ k_g, const float* __restrict__ k_be,
    float* __restrict__ qs, float* __restrict__ kT, float2* __restrict__ xm)
{
    const int blk = blockIdx.x;
    const int tid = threadIdx.x;          // 0..127

    __shared__ __align__(16) float e[4][128];
    __shared__ __align__(16) float4 red[128];
    __shared__ __align__(16) float proj[4][128];
    __shared__ __align__(16) float2 tile[32][65];

    if (blk >= 1056) {
        const int b  = blk - 1056;
        const int cg = tid >> 6;          // 0..1
        const int tt = tid & 63;
        for (int t0 = 0; t0 < 512; t0 += 64) {
            for (int c16 = 0; c16 < 16; ++c16) {
                const int c = c16*2 + cg;
                const float m = mask [(size_t)(b*32 + c)*512 + t0 + tt];
                const float x = input[(size_t)(b*32 + c)*512 + t0 + tt];
                const float mm = 1.0f - m;
                tile[c][tt] = make_float2(x*mm, mm);
            }
            __syncthreads();
            const int c2 = tid & 31;
            const int tg = tid >> 5;      // 0..3
            #pragma unroll
            for (int k = 0; k < 16; ++k) {
                const int t = tg*16 + k;
                xm[((size_t)b*512 + t0 + t)*32 + c2] = tile[c2][t];
            }
            __syncthreads();
        }
        return;
    }

    const bool isq = blk < 32;
    float tv[4];
    int kidx0 = 0;
    if (isq) {
        const int q0 = blk * 4;
        #pragma unroll
        for (int r = 0; r < 4; ++r) tv[r] = (float)(q0 + r) * (1.0f/127.0f);
    } else {
        kidx0 = (blk - 32) * 4;
        #pragma unroll
        for (int r = 0; r < 4; ++r) tv[r] = timesteps[kidx0 + r];
    }

    float pwj = 0.f, pbj = 0.f;
    if (tid > 0) { pwj = pw[tid-1]; pbj = pb[tid-1]; }
    const float lw0 = lw[0], lb0 = lb[0];
    #pragma unroll
    for (int r = 0; r < 4; ++r)
        e[r][tid] = (tid == 0) ? (tv[r]*lw0 + lb0) : sinf(tv[r]*pwj + pbj);
    __syncthreads();

    const float* W  = isq ? q_w  : k_w;
    const float* Bv = isq ? q_b  : k_b;
    const float* G  = isq ? q_g  : k_g;
    const float* Be = isq ? q_be : k_be;

    {
        const int jj = tid >> 2, dc = tid & 3;
        const float4* e0 = (const float4*)(&e[0][0]);
        const float4* e1 = (const float4*)(&e[1][0]);
        const float4* e2 = (const float4*)(&e[2][0]);
        const float4* e3 = (const float4*)(&e[3][0]);
        #pragma unroll
        for (int jb = 0; jb < 4; ++jb) {
            const int j = jb*32 + jj;
            const float4* wrow = (const float4*)(W + (size_t)j*128);
            float a0=0.f, a1=0.f, a2=0.f, a3=0.f;
            #pragma unroll
            for (int k = 0; k < 8; ++k) {
                const int idx = dc + 4*k;
                const float4 w4 = wrow[idx];
                a0 += dot4(w4, e0[idx]);
                a1 += dot4(w4, e1[idx]);
                a2 += dot4(w4, e2[idx]);
                a3 += dot4(w4, e3[idx]);
            }
            a0 += __shfl_xor(a0, 1, 4); a0 += __shfl_xor(a0, 2, 4);
            a1 += __shfl_xor(a1, 1, 4); a1 += __shfl_xor(a1, 2, 4);
            a2 += __shfl_xor(a2, 1, 4); a2 += __shfl_xor(a2, 2, 4);
            a3 += __shfl_xor(a3, 1, 4); a3 += __shfl_xor(a3, 2, 4);
            if (dc == 0) {
                const float bj = Bv[j];
                proj[0][j] = a0 + bj; proj[1][j] = a1 + bj;
                proj[2][j] = a2 + bj; proj[3][j] = a3 + bj;
            }
        }
    }
    __syncthreads();

    float acc[4];
    #pragma unroll
    for (int r = 0; r < 4; ++r) acc[r] = proj[r][tid];

    red[tid] = make_float4(acc[0], acc[1], acc[2], acc[3]);
    __syncthreads();
    for (int s = 64; s > 0; s >>= 1) {
        if (tid < s) {
            float4 m = red[tid]; const float4 o = red[tid+s];
            m.x += o.x; m.y += o.y; m.z += o.z; m.w += o.w;
            red[tid] = m;
        }
        __syncthreads();
    }
    float4 mean = red[0];
    mean.x *= (1.0f/128.0f); mean.y *= (1.0f/128.0f);
    mean.z *= (1.0f/128.0f); mean.w *= (1.0f/128.0f);
    __syncthreads();
    const float d0 = acc[0]-mean.x, d1 = acc[1]-mean.y,
                d2 = acc[2]-mean.z, d3 = acc[3]-mean.w;
    red[tid] = make_float4(d0*d0, d1*d1, d2*d2, d3*d3);
    __syncthreads();
    for (int s = 64; s > 0; s >>= 1) {
        if (tid < s) {
            float4 m = red[tid]; const float4 o = red[tid+s];
            m.x += o.x; m.y += o.y; m.z += o.z; m.w += o.w;
            red[tid] = m;
        }
        __syncthreads();
    }
    float4 var = red[0];
    var.x *= (1.0f/128.0f); var.y *= (1.0f/128.0f);
    var.z *= (1.0f/128.0f); var.w *= (1.0f/128.0f);

    const float gg = G[tid], bb = Be[tid];
    const float o0 = d0*rsqrtf(var.x+LN_EPS)*gg + bb;
    const float o1 = d1*rsqrtf(var.y+LN_EPS)*gg + bb;
    const float o2 = d2*rsqrtf(var.z+LN_EPS)*gg + bb;
    const float o3 = d3*rsqrtf(var.w+LN_EPS)*gg + bb;

    if (isq) {
        const float sc = 0.08838834764831845f;   // 1/sqrt(128)
        const int q0 = blk*4;
        qs[(size_t)(q0+0)*128 + tid] = o0*sc;
        qs[(size_t)(q0+1)*128 + tid] = o1*sc;
        qs[(size_t)(q0+2)*128 + tid] = o2*sc;
        qs[(size_t)(q0+3)*128 + tid] = o3*sc;
    } else {
        const int b = kidx0 >> 9;
        const int t = kidx0 & 511;
        *(float4*)(kT + ((size_t)(b*128 + tid))*512 + t) =
            make_float4(o0, o1, o2, o3);
    }
}

// ---------------------------------------------------------------------------
// Kernel 2: attention. 256 blocks = (b, 4 qi), 256 threads.
// ---------------------------------------------------------------------------
__global__ void __launch_bounds__(256) k_attn(
    const float2* __restrict__ xm,
    const float* __restrict__ qs, const float* __restrict__ kT,
    const float* __restrict__ attn_g, const float* __restrict__ attn_b,
    const float* __restrict__ out_w, const float* __restrict__ out_b,
    const float* __restrict__ out_g, const float* __restrict__ out_be,
    float* __restrict__ outm)
{
    const int b     = blockIdx.x >> 5;
    const int qbase = (blockIdx.x & 31) * 4;
    const int tid   = threadIdx.x;          // 0..255

    __shared__ __align__(16) float et[4][512];
    __shared__ __align__(16) float qsh[4][128];
    __shared__ __align__(16) float wsh[128*66];
    __shared__ __align__(16) float sA[4][8][32];
    __shared__ __align__(16) float aA[4][8][32];
    __shared__ __align__(16) float x2s[4][64];
    __shared__ float redC[4];

    for (int idx = tid; idx < 512; idx += 256)
        qsh[idx >> 7][idx & 127] = qs[(size_t)(qbase + (idx >> 7))*128 + (idx & 127)];
    for (int idx = tid; idx < 8192; idx += 256)
        wsh[(idx >> 6)*66 + (idx & 63)] = out_w[idx];
    __syncthreads();

    {
        const int grp = tid >> 7;
        const int tl  = tid & 127;
        const int q0  = grp*2;
        const float4* kp = (const float4*)kT + (size_t)b*128*128 + tl;
        float4 a0 = make_float4(0,0,0,0), a1 = make_float4(0,0,0,0);
        for (int d = 0; d < 128; ++d) {
            const float4 kv = kp[(size_t)d*128];
            const float qa = qsh[q0][d], qb = qsh[q0+1][d];
            a0.x += qa*kv.x; a0.y += qa*kv.y; a0.z += qa*kv.z; a0.w += qa*kv.w;
            a1.x += qb*kv.x; a1.y += qb*kv.y; a1.z += qb*kv.z; a1.w += qb*kv.w;
        }
        a0.x = __expf(a0.x); a0.y = __expf(a0.y); a0.z = __expf(a0.z); a0.w = __expf(a0.w);
        a1.x = __expf(a1.x); a1.y = __expf(a1.y); a1.z = __expf(a1.z); a1.w = __expf(a1.w);
        ((float4*)et[q0])[tl]   = a0;
        ((float4*)et[q0+1])[tl] = a1;
    }
    __syncthreads();

    {
        const int c   = tid & 31;
        const int seg = tid >> 5;
        const float2* xp = xm + ((size_t)b*512 + seg*64)*32 + c;
        float s0=0,s1=0,s2=0,s3=0, a0=0,a1=0,a2=0,a3=0;
        #pragma unroll 4
        for (int i = 0; i < 64; ++i) {
            const float2 v = xp[(size_t)i*32];
            const int t = seg*64 + i;
            const float w0 = et[0][t]*v.y, w1 = et[1][t]*v.y;
            const float w2 = et[2][t]*v.y, w3 = et[3][t]*v.y;
            s0 += w0; s1 += w1; s2 += w2; s3 += w3;
            a0 += w0*v.x; a1 += w1*v.x; a2 += w2*v.x; a3 += w3*v.x;
        }
        sA[0][seg][c]=s0; sA[1][seg][c]=s1; sA[2][seg][c]=s2; sA[3][seg][c]=s3;
        aA[0][seg][c]=a0; aA[1][seg][c]=a1; aA[2][seg][c]=a2; aA[3][seg][c]=a3;
    }
    __syncthreads();

    {
        const int ql = tid >> 6;
        const int c2 = tid & 63;
        const int cc = c2 & 31;
        float ss = 0.f;
        #pragma unroll
        for (int g = 0; g < 8; ++g) ss += sA[ql][g][cc];
        float attv;
        if (c2 < 32) {
            float aa = 0.f;
            #pragma unroll
            for (int g = 0; g < 8; ++g) aa += aA[ql][g][cc];
            attv = (ss > 0.f) ? aa/ss : 0.f;
        } else {
            attv = (ss > 0.f) ? 1.0f : 0.0f;
        }
        const float mean = wsum64(attv) * (1.0f/64.0f);
        const float dv = attv - mean;
        const float var = wsum64(dv*dv) * (1.0f/64.0f);
        x2s[ql][c2] = dv*rsqrtf(var+LN_EPS)*attn_g[c2] + attn_b[c2];
    }
    __syncthreads();

    {
        const int jhalf = tid >> 7;
        const int j     = tid & 127;
        const int wave  = tid >> 6;
        for (int lq2 = 0; lq2 < 2; ++lq2) {
            const int ql = jhalf*2 + lq2;
            float acc = out_b[j];
            const float4* wrow = (const float4*)(wsh + j*66);
            const float4* xr   = (const float4*)x2s[ql];
            #pragma unroll
            for (int k = 0; k < 16; ++k) acc += dot4(wrow[k], xr[k]);

            float v = wsum64(acc);
            if ((tid & 63) == 0) redC[wave] = v;
            __syncthreads();
            const float mean = (redC[jhalf*2] + redC[jhalf*2+1]) * (1.0f/128.0f);
            __syncthreads();
            const float d = acc - mean;
            v = wsum64(d*d);
            if ((tid & 63) == 0) redC[wave] = v;
            __syncthreads();
            const float var = (redC[jhalf*2] + redC[jhalf*2+1]) * (1.0f/128.0f);
            outm[((size_t)b*128 + qbase + ql)*128 + j] =
                d*rsqrtf(var+LN_EPS)*out_g[j] + out_be[j];
            __syncthreads();
        }
    }
}

// ---------------------------------------------------------------------------
// Kernel 3: gi[qi][b][g] = outm[b,qi,:]·wih[g,:] + bih[g]
// ---------------------------------------------------------------------------
__global__ void k_gi(const float* __restrict__ outm,
                     const float* __restrict__ wih, const float* __restrict__ bih,
                     float* __restrict__ gi)
{
    const int qi  = blockIdx.x;
    const int tid = threadIdx.x;   // 0..383
    __shared__ __align__(16) float rows[8][128];
    for (int idx = tid; idx < 1024; idx += 384) {
        const int b = idx >> 7, d = idx & 127;
        rows[b][d] = outm[(size_t)(b*128+qi)*128 + d];
    }
    __syncthreads();

    const int g0 = tid >> 2, dc = tid & 3;
    #pragma unroll
    for (int gb = 0; gb < 4; ++gb) {
        const int g = gb*96 + g0;
        const float4* wrow = (const float4*)(wih + (size_t)g*128);
        float acc[8] = {0,0,0,0,0,0,0,0};
        #pragma unroll
        for (int k = 0; k < 8; ++k) {
            const int idx = dc + 4*k;
            const float4 w4 = wrow[idx];
            #pragma unroll
            for (int b = 0; b < 8; ++b)
                acc[b] += dot4(w4, ((const float4*)rows[b])[idx]);
        }
        #pragma unroll
        for (int b = 0; b < 8; ++b) {
            acc[b] += __shfl_xor(acc[b], 1, 4);
            acc[b] += __shfl_xor(acc[b], 2, 4);
        }
        if (dc == 0) {
            const float bi = bih[g];
            #pragma unroll
            for (int b = 0; b < 8; ++b)
                gi[((size_t)qi*8 + b)*384 + g] = acc[b] + bi;
        }
    }
}

// ---------------------------------------------------------------------------
// Kernel 4: GRU + fused classifier. 8 blocks x 512 threads.
// Thread (s = tid>>7 in 0..3, u = tid&127): 3 gate rows x 32-float k-slice,
// weights as 48 fp16-PAIR registers, dot via v_dot2_f32_f16 (fp32 accum).
// RESIDENCY GUARANTEE: weights staged global->LDS (fp16), copied LDS->regs
// pre-loop; the SAME LDS region is then reused for h/partials which the loop
// WRITES -> pre-loop ds_reads alias in-loop ds_writes -> compiler cannot
// sink/remat them (R4-R6 showed hints can't stop it; aliasing makes it
// illegal). Ask ~90 VGPR < any occupancy cap -> no spill either.
// h stored in LDS as fp16 pairs (recurrence state stays fp32 in registers).
// ---------------------------------------------------------------------------
__global__ void __launch_bounds__(512) k_gru_cls(
    const float* __restrict__ gi,
    const float* __restrict__ whh, const float* __restrict__ bhh,
    const float* __restrict__ c1w, const float* __restrict__ c1b,
    const float* __restrict__ c2w, const float* __restrict__ c2b,
    const float* __restrict__ c3w, const float* __restrict__ c3b,
    float* __restrict__ out)
{
    const int b   = blockIdx.x;
    const int tid = threadIdx.x;                 // 0..511
    const int s   = tid >> 7;                    // k-slice 0..3
    const int u   = tid & 127;                   // unit

    // 384 rows x 66 uints (64 fp16-pairs + 2 pad): 101,376 B. Reused in-loop:
    //   hP   = lds[0..64)           h as fp16 pairs
    //   part = (float*)&lds[64]     [slice-1][gate][u], 1152 floats
    //   hcls = (float*)&lds[1216]   final h fp32 for classifier
    __shared__ __align__(16) unsigned int lds[25344];
    unsigned int* hP  = lds;
    float* part = (float*)&lds[64];
    float* hcls = (float*)&lds[1216];

    // ---- stage whh -> fp16 pairs in LDS (coalesced global reads) ----
    {
        const float4* w4 = (const float4*)whh;   // 12288 float4
        #pragma unroll 4
        for (int k = 0; k < 24; ++k) {
            const int idx = tid + k*512;
            const float4 v = w4[idx];
            const int row = idx >> 5, c4 = idx & 31;
            h2v p0; p0[0] = (_Float16)v.x; p0[1] = (_Float16)v.y;
            h2v p1; p1[0] = (_Float16)v.z; p1[1] = (_Float16)v.w;
            lds[row*66 + c4*2    ] = __builtin_bit_cast(unsigned int, p0);
            lds[row*66 + c4*2 + 1] = __builtin_bit_cast(unsigned int, p1);
        }
    }
    __syncthreads();

    // ---- copy my 48 weight pairs to registers ----
    unsigned int wreg[3][16];
    #pragma unroll
    for (int g = 0; g < 3; ++g) {
        const uint2* src = (const uint2*)&lds[(g*128 + u)*66 + 16*s];
        #pragma unroll
        for (int i = 0; i < 8; ++i) {
            const uint2 t = src[i];
            wreg[g][2*i] = t.x; wreg[g][2*i+1] = t.y;
        }
    }
    __syncthreads();

    // ---- init h = 0, load biases / step-0 gi ----
    const float* gbase = gi + (size_t)b*384;
    float bh_r=0.f, bh_z=0.f, bh_n=0.f, gr0=0.f, gz0=0.f, gn0=0.f, hprev=0.f;
    if (tid < 64) hP[tid] = 0u;
    if (s == 0) {
        bh_r = bhh[u]; bh_z = bhh[u+128]; bh_n = bhh[u+256];
        gr0 = gbase[u]; gz0 = gbase[u+128]; gn0 = gbase[u+256];
    }
    __syncthreads();

    for (int qi = 0; qi < 128; ++qi) {
        // partial dot over my 16 pairs (broadcast LDS reads, conflict-free)
        const uint4* hp4 = (const uint4*)hP + s*4;
        float ar = 0.f, az = 0.f, an = 0.f;
        #pragma unroll
        for (int i = 0; i < 4; ++i) {
            const uint4 hv = hp4[i];
            ar = fdot2u(wreg[0][4*i+0], hv.x, ar);
            ar = fdot2u(wreg[0][4*i+1], hv.y, ar);
            ar = fdot2u(wreg[0][4*i+2], hv.z, ar);
            ar = fdot2u(wreg[0][4*i+3], hv.w, ar);
            az = fdot2u(wreg[1][4*i+0], hv.x, az);
            az = fdot2u(wreg[1][4*i+1], hv.y, az);
            az = fdot2u(wreg[1][4*i+2], hv.z, az);
            az = fdot2u(wreg[1][4*i+3], hv.w, az);
            an = fdot2u(wreg[2][4*i+0], hv.x, an);
            an = fdot2u(wreg[2][4*i+1], hv.y, an);
            an = fdot2u(wreg[2][4*i+2], hv.z, an);
            an = fdot2u(wreg[2][4*i+3], hv.w, an);
        }
        if (s > 0) {
            float* p = part + (s-1)*384;
            p[u] = ar; p[u+128] = az; p[u+256] = an;
        }

        // prefetch next step's gi triple while partials drain
        float grn=0.f, gzn=0.f, gnn=0.f;
        if (s == 0 && qi < 127) {
            const float* gb = gbase + (size_t)(qi+1)*3072;
            grn = gb[u]; gzn = gb[u+128]; gnn = gb[u+256];
        }
        __syncthreads();

        if (s == 0) {
            const float ghr = ar + part[u]     + part[384+u]     + part[768+u]     + bh_r;
            const float ghz = az + part[128+u] + part[384+128+u] + part[768+128+u] + bh_z;
            const float ghn = an + part[256+u] + part[384+256+u] + part[768+256+u] + bh_n;
            const float r = fast_sigmoid(gr0 + ghr);
            const float z = fast_sigmoid(gz0 + ghz);
            const float n = fast_tanh(gn0 + r*ghn);
            const float hn2 = (1.f - z)*n + z*hprev;
            hprev = hn2;
            gr0 = grn; gz0 = gzn; gn0 = gnn;
            // pack fp16 pair (u even packs h_u, h_{u+1})
            const float other = __shfl_xor(hn2, 1);
            if ((u & 1) == 0) {
                h2v hp; hp[0] = (_Float16)hn2; hp[1] = (_Float16)other;
                hP[u >> 1] = __builtin_bit_cast(unsigned int, hp);
            }
        }
        __syncthreads();
    }

    // ---- fused classifier MLP (fp32 h from registers) ----
    if (s == 0) hcls[u] = hprev;
    __syncthreads();
    if (tid < 128) {
        float acc = c1b[u];
        const float4* wc = (const float4*)(c1w + (size_t)u*128);
        const float4* v  = (const float4*)hcls;
        #pragma unroll
        for (int d4 = 0; d4 < 32; ++d4) acc += dot4(wc[d4], v[d4]);
        part[u] = fmaxf(acc, 0.f);
    }
    __syncthreads();
    if (tid < 128) {
        float acc = c2b[u];
        const float4* wc = (const float4*)(c2w + (size_t)u*128);
        const float4* v  = (const float4*)part;
        #pragma unroll
        for (int d4 = 0; d4 < 32; ++d4) acc += dot4(wc[d4], v[d4]);
        part[384 + u] = fmaxf(acc, 0.f);
    }
    __syncthreads();
    if (tid < 2) {
        float acc = c3b[tid];
        const float4* wc = (const float4*)(c3w + (size_t)tid*128);
        const float4* v  = (const float4*)(part + 384);
        #pragma unroll
        for (int d4 = 0; d4 < 32; ++d4) acc += dot4(wc[d4], v[d4]);
        out[(size_t)b*2 + tid] = acc;
    }
}

// ---------------------------------------------------------------------------
extern "C" void kernel_launch(void* const* d_in, const int* in_sizes, int n_in,
                              void* d_out, int out_size, void* d_ws, size_t ws_size,
                              hipStream_t stream)
{
    const float* input     = (const float*)d_in[0];
    const float* mask      = (const float*)d_in[1];
    const float* timesteps = (const float*)d_in[2];
    const float* pw        = (const float*)d_in[3];
    const float* pb        = (const float*)d_in[4];
    const float* lw        = (const float*)d_in[5];
    const float* lb        = (const float*)d_in[6];
    const float* q_w       = (const float*)d_in[7];
    const float* q_b       = (const float*)d_in[8];
    const float* q_g       = (const float*)d_in[9];
    const float* q_be      = (const float*)d_in[10];
    const float* k_w       = (const float*)d_in[11];
    const float* k_b       = (const float*)d_in[12];
    const float* k_g       = (const float*)d_in[13];
    const float* k_be      = (const float*)d_in[14];
    const float* attn_g    = (const float*)d_in[15];
    const float* attn_b    = (const float*)d_in[16];
    const float* out_w     = (const float*)d_in[17];
    const float* out_b     = (const float*)d_in[18];
    const float* out_g     = (const float*)d_in[19];
    const float* out_be    = (const float*)d_in[20];
    const float* gru_wih   = (const float*)d_in[21];
    const float* gru_whh   = (const float*)d_in[22];
    const float* gru_bih   = (const float*)d_in[23];
    const float* gru_bhh   = (const float*)d_in[24];
    const float* c1_w      = (const float*)d_in[25];
    const float* c1_b      = (const float*)d_in[26];
    const float* c2_w      = (const float*)d_in[27];
    const float* c2_b      = (const float*)d_in[28];
    const float* c3_w      = (const float*)d_in[29];
    const float* c3_b      = (const float*)d_in[30];

    float* ws   = (float*)d_ws;
    float*  qs   = ws;                    // 128*128             = 16384
    float*  kT   = qs   + 16384;          // 8*128*512           = 524288
    float*  outm = kT   + 524288;         // 8*128*128           = 131072
    float*  gi   = outm + 131072;         // 128*8*384           = 393216
    float2* xm   = (float2*)(gi + 393216);// 8*512*32 float2     = 262144 floats

    k_embed_proj<<<1064, 128, 0, stream>>>(input, mask, timesteps,
                                           pw, pb, lw, lb,
                                           q_w, q_b, q_g, q_be,
                                           k_w, k_b, k_g, k_be, qs, kT, xm);
    k_attn<<<256, 256, 0, stream>>>(xm, qs, kT,
                                    attn_g, attn_b, out_w, out_b,
                                    out_g, out_be, outm);
    k_gi<<<128, 384, 0, stream>>>(outm, gru_wih, gru_bih, gi);
    k_gru_cls<<<8, 512, 0, stream>>>(gi, gru_whh, gru_bhh,
                                     c1_w, c1_b, c2_w, c2_b, c3_w, c3_b,
                                     (float*)d_out);
}

// Round 8
// 240.525 us; speedup vs baseline: 1.6040x; 1.0912x over previous
//
#include <hip/hip_runtime.h>
#include <math.h>

#define LN_EPS 1e-5f

typedef _Float16 h2v __attribute__((ext_vector_type(2)));

__device__ __forceinline__ float dot4(float4 a, float4 b) {
    return a.x*b.x + a.y*b.y + a.z*b.z + a.w*b.w;
}
__device__ __forceinline__ void fma4(float4& a, float s, float4 v) {
    a.x += s*v.x; a.y += s*v.y; a.z += s*v.z; a.w += s*v.w;
}
__device__ __forceinline__ float fast_rcp(float x) {
    return __builtin_amdgcn_rcpf(x);       // v_rcp_f32: 1 instr vs ~10-op IEEE div
}
__device__ __forceinline__ float fast_sigmoid(float x) {
    return fast_rcp(1.f + __expf(-x));     // +-inf safe
}
__device__ __forceinline__ float fast_tanh(float x) {
    return 1.f - 2.f*fast_rcp(__expf(2.f*x) + 1.f);   // +-inf safe
}
__device__ __forceinline__ float fdot2u(unsigned int a, unsigned int b, float c) {
#if __has_builtin(__builtin_amdgcn_fdot2)
    return __builtin_amdgcn_fdot2(__builtin_bit_cast(h2v, a),
                                  __builtin_bit_cast(h2v, b), c, false);
#else
    const h2v av = __builtin_bit_cast(h2v, a);
    const h2v bv = __builtin_bit_cast(h2v, b);
    return c + (float)av[0]*(float)bv[0] + (float)av[1]*(float)bv[1];
#endif
}
__device__ __forceinline__ float wsum64(float v) {
    #pragma unroll
    for (int off = 32; off > 0; off >>= 1) v += __shfl_xor(v, off);
    return v;
}

// ---------------------------------------------------------------------------
// Kernel 1: blocks 0..63 = xm transpose (FIRST, so the cold-HBM mask/input
// reads overlap the compute blocks instead of running as an 8-block tail);
// blocks 64..95 = query rows (4/blk); 96..1119 = key rows (4/blk)-> kT[b][d][t].
// ---------------------------------------------------------------------------
__global__ void k_embed_proj(
    const float* __restrict__ input, const float* __restrict__ mask,
    const float* __restrict__ timesteps,
    const float* __restrict__ pw, const float* __restrict__ pb,
    const float* __restrict__ lw, const float* __restrict__ lb,
    const float* __restrict__ q_w, const float* __restrict__ q_b,
    const float* __restrict__ q_g, const float* __restrict__ q_be,
    const float* __restrict__ k_w, const float* __restrict__ k_b,
    const float* __restrict__ k_g, const float* __restrict__ k_be,
    float* __restrict__ qs, float* __restrict__ kT, float2* __restrict__ xm)
{
    const int blk = blockIdx.x;
    const int tid = threadIdx.x;          // 0..127

    __shared__ __align__(16) float e[4][128];
    __shared__ __align__(16) float4 red[128];
    __shared__ __align__(16) float proj[4][128];
    __shared__ __align__(16) float2 tile[32][65];

    if (blk < 64) {
        // ---- xm transpose: 8 blocks per b, 64 t each ----
        const int b  = blk >> 3;
        const int t0 = (blk & 7) * 64;
        const int cg = tid >> 6;          // 0..1
        const int tt = tid & 63;
        #pragma unroll
        for (int c16 = 0; c16 < 16; ++c16) {
            const int c = c16*2 + cg;
            const float m = mask [(size_t)(b*32 + c)*512 + t0 + tt];
            const float x = input[(size_t)(b*32 + c)*512 + t0 + tt];
            const float mm = 1.0f - m;
            tile[c][tt] = make_float2(x*mm, mm);
        }
        __syncthreads();
        const int c2 = tid & 31;
        const int tg = tid >> 5;          // 0..3
        #pragma unroll
        for (int k = 0; k < 16; ++k) {
            const int t = tg*16 + k;
            xm[((size_t)b*512 + t0 + t)*32 + c2] = tile[c2][t];
        }
        return;
    }

    const bool isq = blk < 96;
    float tv[4];
    int kidx0 = 0;
    if (isq) {
        const int q0 = (blk - 64) * 4;
        #pragma unroll
        for (int r = 0; r < 4; ++r) tv[r] = (float)(q0 + r) * (1.0f/127.0f);
    } else {
        kidx0 = (blk - 96) * 4;
        #pragma unroll
        for (int r = 0; r < 4; ++r) tv[r] = timesteps[kidx0 + r];
    }

    float pwj = 0.f, pbj = 0.f;
    if (tid > 0) { pwj = pw[tid-1]; pbj = pb[tid-1]; }
    const float lw0 = lw[0], lb0 = lb[0];
    #pragma unroll
    for (int r = 0; r < 4; ++r)
        e[r][tid] = (tid == 0) ? (tv[r]*lw0 + lb0) : sinf(tv[r]*pwj + pbj);
    __syncthreads();

    const float* W  = isq ? q_w  : k_w;
    const float* Bv = isq ? q_b  : k_b;
    const float* G  = isq ? q_g  : k_g;
    const float* Be = isq ? q_be : k_be;

    {
        const int jj = tid >> 2, dc = tid & 3;
        const float4* e0 = (const float4*)(&e[0][0]);
        const float4* e1 = (const float4*)(&e[1][0]);
        const float4* e2 = (const float4*)(&e[2][0]);
        const float4* e3 = (const float4*)(&e[3][0]);
        #pragma unroll
        for (int jb = 0; jb < 4; ++jb) {
            const int j = jb*32 + jj;
            const float4* wrow = (const float4*)(W + (size_t)j*128);
            float a0=0.f, a1=0.f, a2=0.f, a3=0.f;
            #pragma unroll
            for (int k = 0; k < 8; ++k) {
                const int idx = dc + 4*k;
                const float4 w4 = wrow[idx];
                a0 += dot4(w4, e0[idx]);
                a1 += dot4(w4, e1[idx]);
                a2 += dot4(w4, e2[idx]);
                a3 += dot4(w4, e3[idx]);
            }
            a0 += __shfl_xor(a0, 1, 4); a0 += __shfl_xor(a0, 2, 4);
            a1 += __shfl_xor(a1, 1, 4); a1 += __shfl_xor(a1, 2, 4);
            a2 += __shfl_xor(a2, 1, 4); a2 += __shfl_xor(a2, 2, 4);
            a3 += __shfl_xor(a3, 1, 4); a3 += __shfl_xor(a3, 2, 4);
            if (dc == 0) {
                const float bj = Bv[j];
                proj[0][j] = a0 + bj; proj[1][j] = a1 + bj;
                proj[2][j] = a2 + bj; proj[3][j] = a3 + bj;
            }
        }
    }
    __syncthreads();

    float acc[4];
    #pragma unroll
    for (int r = 0; r < 4; ++r) acc[r] = proj[r][tid];

    red[tid] = make_float4(acc[0], acc[1], acc[2], acc[3]);
    __syncthreads();
    for (int s = 64; s > 0; s >>= 1) {
        if (tid < s) {
            float4 m = red[tid]; const float4 o = red[tid+s];
            m.x += o.x; m.y += o.y; m.z += o.z; m.w += o.w;
            red[tid] = m;
        }
        __syncthreads();
    }
    float4 mean = red[0];
    mean.x *= (1.0f/128.0f); mean.y *= (1.0f/128.0f);
    mean.z *= (1.0f/128.0f); mean.w *= (1.0f/128.0f);
    __syncthreads();
    const float d0 = acc[0]-mean.x, d1 = acc[1]-mean.y,
                d2 = acc[2]-mean.z, d3 = acc[3]-mean.w;
    red[tid] = make_float4(d0*d0, d1*d1, d2*d2, d3*d3);
    __syncthreads();
    for (int s = 64; s > 0; s >>= 1) {
        if (tid < s) {
            float4 m = red[tid]; const float4 o = red[tid+s];
            m.x += o.x; m.y += o.y; m.z += o.z; m.w += o.w;
            red[tid] = m;
        }
        __syncthreads();
    }
    float4 var = red[0];
    var.x *= (1.0f/128.0f); var.y *= (1.0f/128.0f);
    var.z *= (1.0f/128.0f); var.w *= (1.0f/128.0f);

    const float gg = G[tid], bb = Be[tid];
    const float o0 = d0*rsqrtf(var.x+LN_EPS)*gg + bb;
    const float o1 = d1*rsqrtf(var.y+LN_EPS)*gg + bb;
    const float o2 = d2*rsqrtf(var.z+LN_EPS)*gg + bb;
    const float o3 = d3*rsqrtf(var.w+LN_EPS)*gg + bb;

    if (isq) {
        const float sc = 0.08838834764831845f;   // 1/sqrt(128)
        const int q0 = (blk - 64)*4;
        qs[(size_t)(q0+0)*128 + tid] = o0*sc;
        qs[(size_t)(q0+1)*128 + tid] = o1*sc;
        qs[(size_t)(q0+2)*128 + tid] = o2*sc;
        qs[(size_t)(q0+3)*128 + tid] = o3*sc;
    } else {
        const int b = kidx0 >> 9;
        const int t = kidx0 & 511;
        *(float4*)(kT + ((size_t)(b*128 + tid))*512 + t) =
            make_float4(o0, o1, o2, o3);
    }
}

// ---------------------------------------------------------------------------
// Kernel 2: attention. 256 blocks = (b, 4 qi), 256 threads.
// Score loop software-pipelined 4 loads deep (in-order issue exposed ~200cyc
// L2 latency per iter at 1 blk/CU otherwise).
// ---------------------------------------------------------------------------
__global__ void __launch_bounds__(256) k_attn(
    const float2* __restrict__ xm,
    const float* __restrict__ qs, const float* __restrict__ kT,
    const float* __restrict__ attn_g, const float* __restrict__ attn_b,
    const float* __restrict__ out_w, const float* __restrict__ out_b,
    const float* __restrict__ out_g, const float* __restrict__ out_be,
    float* __restrict__ outm)
{
    const int b     = blockIdx.x >> 5;
    const int qbase = (blockIdx.x & 31) * 4;
    const int tid   = threadIdx.x;          // 0..255

    __shared__ __align__(16) float et[4][512];
    __shared__ __align__(16) float qsh[4][128];
    __shared__ __align__(16) float wsh[128*66];
    __shared__ __align__(16) float sA[4][8][32];
    __shared__ __align__(16) float aA[4][8][32];
    __shared__ __align__(16) float x2s[4][64];
    __shared__ float redC[4];

    for (int idx = tid; idx < 512; idx += 256)
        qsh[idx >> 7][idx & 127] = qs[(size_t)(qbase + (idx >> 7))*128 + (idx & 127)];
    for (int idx = tid; idx < 8192; idx += 256)
        wsh[(idx >> 6)*66 + (idx & 63)] = out_w[idx];
    __syncthreads();

    // ---- scores: group handles 2 qi; 4-deep register pipeline on kT ----
    {
        const int grp = tid >> 7;
        const int tl  = tid & 127;
        const int q0  = grp*2;
        const float4* kp  = (const float4*)kT + (size_t)b*128*128 + tl;
        const float4* qa4 = (const float4*)qsh[q0];
        const float4* qb4 = (const float4*)qsh[q0+1];
        float4 a0 = make_float4(0,0,0,0), a1 = make_float4(0,0,0,0);
        float4 c0 = kp[0], c1 = kp[128], c2 = kp[256], c3 = kp[384];
        for (int c = 0; c < 32; ++c) {
            float4 n0, n1, n2, n3;
            if (c < 31) {
                const float4* kn = kp + (size_t)(4*c+4)*128;
                n0 = kn[0]; n1 = kn[128]; n2 = kn[256]; n3 = kn[384];
            }
            const float4 qa = qa4[c], qb = qb4[c];
            fma4(a0, qa.x, c0); fma4(a1, qb.x, c0);
            fma4(a0, qa.y, c1); fma4(a1, qb.y, c1);
            fma4(a0, qa.z, c2); fma4(a1, qb.z, c2);
            fma4(a0, qa.w, c3); fma4(a1, qb.w, c3);
            c0 = n0; c1 = n1; c2 = n2; c3 = n3;
        }
        a0.x = __expf(a0.x); a0.y = __expf(a0.y); a0.z = __expf(a0.z); a0.w = __expf(a0.w);
        a1.x = __expf(a1.x); a1.y = __expf(a1.y); a1.z = __expf(a1.z); a1.w = __expf(a1.w);
        ((float4*)et[q0])[tl]   = a0;
        ((float4*)et[q0+1])[tl] = a1;
    }
    __syncthreads();

    {
        const int c   = tid & 31;
        const int seg = tid >> 5;
        const float2* xp = xm + ((size_t)b*512 + seg*64)*32 + c;
        float s0=0,s1=0,s2=0,s3=0, a0=0,a1=0,a2=0,a3=0;
        #pragma unroll 4
        for (int i = 0; i < 64; ++i) {
            const float2 v = xp[(size_t)i*32];
            const int t = seg*64 + i;
            const float w0 = et[0][t]*v.y, w1 = et[1][t]*v.y;
            const float w2 = et[2][t]*v.y, w3 = et[3][t]*v.y;
            s0 += w0; s1 += w1; s2 += w2; s3 += w3;
            a0 += w0*v.x; a1 += w1*v.x; a2 += w2*v.x; a3 += w3*v.x;
        }
        sA[0][seg][c]=s0; sA[1][seg][c]=s1; sA[2][seg][c]=s2; sA[3][seg][c]=s3;
        aA[0][seg][c]=a0; aA[1][seg][c]=a1; aA[2][seg][c]=a2; aA[3][seg][c]=a3;
    }
    __syncthreads();

    {
        const int ql = tid >> 6;
        const int c2 = tid & 63;
        const int cc = c2 & 31;
        float ss = 0.f;
        #pragma unroll
        for (int g = 0; g < 8; ++g) ss += sA[ql][g][cc];
        float attv;
        if (c2 < 32) {
            float aa = 0.f;
            #pragma unroll
            for (int g = 0; g < 8; ++g) aa += aA[ql][g][cc];
            attv = (ss > 0.f) ? aa/ss : 0.f;
        } else {
            attv = (ss > 0.f) ? 1.0f : 0.0f;
        }
        const float mean = wsum64(attv) * (1.0f/64.0f);
        const float dv = attv - mean;
        const float var = wsum64(dv*dv) * (1.0f/64.0f);
        x2s[ql][c2] = dv*rsqrtf(var+LN_EPS)*attn_g[c2] + attn_b[c2];
    }
    __syncthreads();

    {
        const int jhalf = tid >> 7;
        const int j     = tid & 127;
        const int wave  = tid >> 6;
        for (int lq2 = 0; lq2 < 2; ++lq2) {
            const int ql = jhalf*2 + lq2;
            float acc = out_b[j];
            const float4* wrow = (const float4*)(wsh + j*66);
            const float4* xr   = (const float4*)x2s[ql];
            #pragma unroll
            for (int k = 0; k < 16; ++k) acc += dot4(wrow[k], xr[k]);

            float v = wsum64(acc);
            if ((tid & 63) == 0) redC[wave] = v;
            __syncthreads();
            const float mean = (redC[jhalf*2] + redC[jhalf*2+1]) * (1.0f/128.0f);
            __syncthreads();
            const float d = acc - mean;
            v = wsum64(d*d);
            if ((tid & 63) == 0) redC[wave] = v;
            __syncthreads();
            const float var = (redC[jhalf*2] + redC[jhalf*2+1]) * (1.0f/128.0f);
            outm[((size_t)b*128 + qbase + ql)*128 + j] =
                d*rsqrtf(var+LN_EPS)*out_g[j] + out_be[j];
            __syncthreads();
        }
    }
}

// ---------------------------------------------------------------------------
// Kernel 3: gi[qi][b][g] = outm[b,qi,:]·wih[g,:] + bih[g]
// ---------------------------------------------------------------------------
__global__ void k_gi(const float* __restrict__ outm,
                     const float* __restrict__ wih, const float* __restrict__ bih,
                     float* __restrict__ gi)
{
    const int qi  = blockIdx.x;
    const int tid = threadIdx.x;   // 0..383
    __shared__ __align__(16) float rows[8][128];
    for (int idx = tid; idx < 1024; idx += 384) {
        const int b = idx >> 7, d = idx & 127;
        rows[b][d] = outm[(size_t)(b*128+qi)*128 + d];
    }
    __syncthreads();

    const int g0 = tid >> 2, dc = tid & 3;
    #pragma unroll
    for (int gb = 0; gb < 4; ++gb) {
        const int g = gb*96 + g0;
        const float4* wrow = (const float4*)(wih + (size_t)g*128);
        float acc[8] = {0,0,0,0,0,0,0,0};
        #pragma unroll
        for (int k = 0; k < 8; ++k) {
            const int idx = dc + 4*k;
            const float4 w4 = wrow[idx];
            #pragma unroll
            for (int b = 0; b < 8; ++b)
                acc[b] += dot4(w4, ((const float4*)rows[b])[idx]);
        }
        #pragma unroll
        for (int b = 0; b < 8; ++b) {
            acc[b] += __shfl_xor(acc[b], 1, 4);
            acc[b] += __shfl_xor(acc[b], 2, 4);
        }
        if (dc == 0) {
            const float bi = bih[g];
            #pragma unroll
            for (int b = 0; b < 8; ++b)
                gi[((size_t)qi*8 + b)*384 + g] = acc[b] + bi;
        }
    }
}

// ---------------------------------------------------------------------------
// Kernel 4: GRU + fused classifier. 8 blocks x 512 threads.
// R7 structure (LDS-alias pinned fp16 weights, VGPR=88, no spill) plus:
//  - v_rcp_f32 sigmoid/tanh (removes 2 IEEE div sequences from the serial
//    gate chain, ~150-250 cyc/step)
//  - partials as one float4 write / 3 b128 reads (was 3+9 b32)
// ---------------------------------------------------------------------------
__global__ void __launch_bounds__(512) k_gru_cls(
    const float* __restrict__ gi,
    const float* __restrict__ whh, const float* __restrict__ bhh,
    const float* __restrict__ c1w, const float* __restrict__ c1b,
    const float* __restrict__ c2w, const float* __restrict__ c2b,
    const float* __restrict__ c3w, const float* __restrict__ c3b,
    float* __restrict__ out)
{
    const int b   = blockIdx.x;
    const int tid = threadIdx.x;                 // 0..511
    const int s   = tid >> 7;                    // k-slice 0..3
    const int u   = tid & 127;                   // unit

    __shared__ __align__(16) unsigned int lds[25344];
    unsigned int* hP = lds;                      // 64 uints (h as fp16 pairs)
    float4* part4 = (float4*)&lds[64];           // 3*128 float4
    float* hcls = (float*)&lds[64 + 1536];       // 128 floats

    // ---- stage whh -> fp16 pairs in LDS (coalesced) ----
    {
        const float4* w4 = (const float4*)whh;   // 12288 float4
        #pragma unroll 4
        for (int k = 0; k < 24; ++k) {
            const int idx = tid + k*512;
            const float4 v = w4[idx];
            const int row = idx >> 5, c4 = idx & 31;
            h2v p0; p0[0] = (_Float16)v.x; p0[1] = (_Float16)v.y;
            h2v p1; p1[0] = (_Float16)v.z; p1[1] = (_Float16)v.w;
            lds[row*66 + c4*2    ] = __builtin_bit_cast(unsigned int, p0);
            lds[row*66 + c4*2 + 1] = __builtin_bit_cast(unsigned int, p1);
        }
    }
    __syncthreads();

    // ---- my 48 weight pairs -> registers (aliased region: cannot be sunk) ----
    unsigned int wreg[3][16];
    #pragma unroll
    for (int g = 0; g < 3; ++g) {
        const uint2* src = (const uint2*)&lds[(g*128 + u)*66 + 16*s];
        #pragma unroll
        for (int i = 0; i < 8; ++i) {
            const uint2 t = src[i];
            wreg[g][2*i] = t.x; wreg[g][2*i+1] = t.y;
        }
    }
    __syncthreads();

    const float* gbase = gi + (size_t)b*384;
    float bh_r=0.f, bh_z=0.f, bh_n=0.f, gr0=0.f, gz0=0.f, gn0=0.f, hprev=0.f;
    if (tid < 64) hP[tid] = 0u;
    if (s == 0) {
        bh_r = bhh[u]; bh_z = bhh[u+128]; bh_n = bhh[u+256];
        gr0 = gbase[u]; gz0 = gbase[u+128]; gn0 = gbase[u+256];
    }
    __syncthreads();

    for (int qi = 0; qi < 128; ++qi) {
        const uint4* hp4 = (const uint4*)hP + s*4;
        float ar = 0.f, az = 0.f, an = 0.f;
        #pragma unroll
        for (int i = 0; i < 4; ++i) {
            const uint4 hv = hp4[i];
            ar = fdot2u(wreg[0][4*i+0], hv.x, ar);
            ar = fdot2u(wreg[0][4*i+1], hv.y, ar);
            ar = fdot2u(wreg[0][4*i+2], hv.z, ar);
            ar = fdot2u(wreg[0][4*i+3], hv.w, ar);
            az = fdot2u(wreg[1][4*i+0], hv.x, az);
            az = fdot2u(wreg[1][4*i+1], hv.y, az);
            az = fdot2u(wreg[1][4*i+2], hv.z, az);
            az = fdot2u(wreg[1][4*i+3], hv.w, az);
            an = fdot2u(wreg[2][4*i+0], hv.x, an);
            an = fdot2u(wreg[2][4*i+1], hv.y, an);
            an = fdot2u(wreg[2][4*i+2], hv.z, an);
            an = fdot2u(wreg[2][4*i+3], hv.w, an);
        }
        if (s > 0) part4[(s-1)*128 + u] = make_float4(ar, az, an, 0.f);

        float grn=0.f, gzn=0.f, gnn=0.f;
        if (s == 0 && qi < 127) {
            const float* gb = gbase + (size_t)(qi+1)*3072;
            grn = gb[u]; gzn = gb[u+128]; gnn = gb[u+256];
        }
        __syncthreads();

        if (s == 0) {
            const float4 p0 = part4[u], p1 = part4[128+u], p2 = part4[256+u];
            const float ghr = ar + p0.x + p1.x + p2.x + bh_r;
            const float ghz = az + p0.y + p1.y + p2.y + bh_z;
            const float ghn = an + p0.z + p1.z + p2.z + bh_n;
            const float r = fast_sigmoid(gr0 + ghr);
            const float z = fast_sigmoid(gz0 + ghz);
            const float n = fast_tanh(gn0 + r*ghn);
            const float hn2 = (1.f - z)*n + z*hprev;
            hprev = hn2;
            gr0 = grn; gz0 = gzn; gn0 = gnn;
            const float other = __shfl_xor(hn2, 1);
            if ((u & 1) == 0) {
                h2v hp; hp[0] = (_Float16)hn2; hp[1] = (_Float16)other;
                hP[u >> 1] = __builtin_bit_cast(unsigned int, hp);
            }
        }
        __syncthreads();
    }

    // ---- fused classifier MLP (fp32 h) ----
    float* scr = (float*)part4;
    if (s == 0) hcls[u] = hprev;
    __syncthreads();
    if (tid < 128) {
        float acc = c1b[u];
        const float4* wc = (const float4*)(c1w + (size_t)u*128);
        const float4* v  = (const float4*)hcls;
        #pragma unroll
        for (int d4 = 0; d4 < 32; ++d4) acc += dot4(wc[d4], v[d4]);
        scr[u] = fmaxf(acc, 0.f);
    }
    __syncthreads();
    if (tid < 128) {
        float acc = c2b[u];
        const float4* wc = (const float4*)(c2w + (size_t)u*128);
        const float4* v  = (const float4*)scr;
        #pragma unroll
        for (int d4 = 0; d4 < 32; ++d4) acc += dot4(wc[d4], v[d4]);
        scr[128 + u] = fmaxf(acc, 0.f);
    }
    __syncthreads();
    if (tid < 2) {
        float acc = c3b[tid];
        const float4* wc = (const float4*)(c3w + (size_t)tid*128);
        const float4* v  = (const float4*)(scr + 128);
        #pragma unroll
        for (int d4 = 0; d4 < 32; ++d4) acc += dot4(wc[d4], v[d4]);
        out[(size_t)b*2 + tid] = acc;
    }
}

// ---------------------------------------------------------------------------
extern "C" void kernel_launch(void* const* d_in, const int* in_sizes, int n_in,
                              void* d_out, int out_size, void* d_ws, size_t ws_size,
                              hipStream_t stream)
{
    const float* input     = (const float*)d_in[0];
    const float* mask      = (const float*)d_in[1];
    const float* timesteps = (const float*)d_in[2];
    const float* pw        = (const float*)d_in[3];
    const float* pb        = (const float*)d_in[4];
    const float* lw        = (const float*)d_in[5];
    const float* lb        = (const float*)d_in[6];
    const float* q_w       = (const float*)d_in[7];
    const float* q_b       = (const float*)d_in[8];
    const float* q_g       = (const float*)d_in[9];
    const float* q_be      = (const float*)d_in[10];
    const float* k_w       = (const float*)d_in[11];
    const float* k_b       = (const float*)d_in[12];
    const float* k_g       = (const float*)d_in[13];
    const float* k_be      = (const float*)d_in[14];
    const float* attn_g    = (const float*)d_in[15];
    const float* attn_b    = (const float*)d_in[16];
    const float* out_w     = (const float*)d_in[17];
    const float* out_b     = (const float*)d_in[18];
    const float* out_g     = (const float*)d_in[19];
    const float* out_be    = (const float*)d_in[20];
    const float* gru_wih   = (const float*)d_in[21];
    const float* gru_whh   = (const float*)d_in[22];
    const float* gru_bih   = (const float*)d_in[23];
    const float* gru_bhh   = (const float*)d_in[24];
    const float* c1_w      = (const float*)d_in[25];
    const float* c1_b      = (const float*)d_in[26];
    const float* c2_w      = (const float*)d_in[27];
    const float* c2_b      = (const float*)d_in[28];
    const float* c3_w      = (const float*)d_in[29];
    const float* c3_b      = (const float*)d_in[30];

    float* ws   = (float*)d_ws;
    float*  qs   = ws;                    // 128*128             = 16384
    float*  kT   = qs   + 16384;          // 8*128*512           = 524288
    float*  outm = kT   + 524288;         // 8*128*128           = 131072
    float*  gi   = outm + 131072;         // 128*8*384           = 393216
    float2* xm   = (float2*)(gi + 393216);// 8*512*32 float2     = 262144 floats

    k_embed_proj<<<1120, 128, 0, stream>>>(input, mask, timesteps,
                                           pw, pb, lw, lb,
                                           q_w, q_b, q_g, q_be,
                                           k_w, k_b, k_g, k_be, qs, kT, xm);
    k_attn<<<256, 256, 0, stream>>>(xm, qs, kT,
                                    attn_g, attn_b, out_w, out_b,
                                    out_g, out_be, outm);
    k_gi<<<128, 384, 0, stream>>>(outm, gru_wih, gru_bih, gi);
    k_gru_cls<<<8, 512, 0, stream>>>(gi, gru_whh, gru_bhh,
                                     c1_w, c1_b, c2_w, c2_b, c3_w, c3_b,
                                     (float*)d_out);
}